// Round 11
// baseline (416.256 us; speedup 1.0000x reference)
//
#include <hip/hip_runtime.h>
#include <hip/hip_bf16.h>

#define NN 8192
#define KF 512
#define FF 64
#define GAT_ALPHA 0.2f
#define MSHIFT 20.0f          // safe upper bound on max_j e2[j] (pre-scale)
#define LOG2E 1.44269504f

#define JSPLIT 8              // grid = 128 row-groups x 8 = 1024 blocks
#define JW (NN / JSPLIT)      // 1024 j per block
#define NSUB 4                // ht sub-tiles per block (double-buffered)
#define SUBJ 256              // j per sub-tile
#define SUBK 8                // k-steps per sub-tile
#define HTS 264               // hs row stride (bf16): 132 dwords %32=4 -> 2-way (free)

#define EXP2F(x) __builtin_amdgcn_exp2f(x)

typedef __attribute__((ext_vector_type(8))) __bf16 bf16x8;
typedef __attribute__((ext_vector_type(4))) float f32x4;
typedef __attribute__((ext_vector_type(4))) int   i32x4;

// RNE fp32->bf16 pair pack, pure bit ops. Returns (bf16(hi)<<16)|bf16(lo).
__device__ __forceinline__ unsigned pack_bf16_rne(float hi, float lo) {
    unsigned uh = __float_as_uint(hi);
    unsigned ul = __float_as_uint(lo);
    uh = uh + 0x7FFFu + ((uh >> 16) & 1u);
    ul = ul + 0x7FFFu + ((ul >> 16) & 1u);
    return (uh & 0xFFFF0000u) | (ul >> 16);
}

// ---------------------------------------------------------------------------
// Kernel A: h = x@W (fp32), e1/e2 = (h@a1, h@a2) * log2(e),
//           ht = h^T bf16 [64][8192]. 256 blocks x 256 thr, 32 rows/block.
// ---------------------------------------------------------------------------
__global__ __launch_bounds__(256) void gat_linear(
    const float* __restrict__ x, const float* __restrict__ W,
    const float* __restrict__ av, __hip_bfloat16* __restrict__ ht,
    float* __restrict__ e1, float* __restrict__ e2)
{
    __shared__ float xs[32][33];
    __shared__ float Ws[32][64];
    __shared__ float ep[2][32][17];

    const int t  = threadIdx.x;
    const int fq = t & 15;
    const int rq = t >> 4;
    const int i0 = blockIdx.x * 32;

    const int kl = t & 31, r0 = t >> 5;
    const int fw = t & 63, kq = t >> 6;

    float acc[2][4] = {};

    for (int kt = 0; kt < KF; kt += 32) {
        #pragma unroll
        for (int m = 0; m < 4; ++m)
            xs[kl][r0 + 8 * m] = x[(size_t)(i0 + r0 + 8 * m) * KF + kt + kl];
        #pragma unroll
        for (int m = 0; m < 8; ++m)
            Ws[kq + 4 * m][fw] = W[(size_t)(kt + kq + 4 * m) * FF + fw];
        __syncthreads();
        #pragma unroll
        for (int kk = 0; kk < 32; ++kk) {
            float x0 = xs[kk][rq * 2];
            float x1 = xs[kk][rq * 2 + 1];
            f32x4 wv = *(const f32x4*)&Ws[kk][fq * 4];
            #pragma unroll
            for (int v = 0; v < 4; ++v) {
                acc[0][v] += x0 * wv[v];
                acc[1][v] += x1 * wv[v];
            }
        }
        __syncthreads();
    }

    #pragma unroll
    for (int v = 0; v < 4; ++v) {
        int f = fq * 4 + v;
        unsigned w = pack_bf16_rne(acc[1][v], acc[0][v]);
        *(unsigned*)&ht[(size_t)f * NN + i0 + rq * 2] = w;
    }

    f32x4 a1v = *(const f32x4*)&av[fq * 4];
    f32x4 a2v = *(const f32x4*)&av[64 + fq * 4];
    #pragma unroll
    for (int u = 0; u < 2; ++u) {
        float s1 = 0.f, s2 = 0.f;
        #pragma unroll
        for (int v = 0; v < 4; ++v) {
            s1 += acc[u][v] * a1v[v];
            s2 += acc[u][v] * a2v[v];
        }
        ep[0][rq * 2 + u][fq] = s1;
        ep[1][rq * 2 + u][fq] = s2;
    }
    __syncthreads();
    if (t < 32) {
        float s1 = 0.f, s2 = 0.f;
        #pragma unroll
        for (int q = 0; q < 16; ++q) { s1 += ep[0][t][q]; s2 += ep[1][t][q]; }
        e1[i0 + t] = s1 * LOG2E;
        e2[i0 + t] = s2 * LOG2E;
    }
}

// ---------------------------------------------------------------------------
// Kernel B: LDS-resident hot loop, software-pipelined sub-tiles.
// Block = 64 rows x 1024 j (JSPLIT=8 -> 4KB contiguous adj per row, better
// DRAM bursts; accs traffic halved). Prologue: adj slice 256KB -> LDS dword
// mask msk32[row][step] (1 conflict-free ds_read_b32/step in loop); e2 4KB;
// ht sub-tile 0. Then 4 sub-tiles: issue next ht loads into regs, compute
// 8 k-steps from LDS, ds_write regs -> other buffer, barrier. VMEM stays
// busy through compute phases (fixes the phase-bursty VMEM idle of R10).
// ---------------------------------------------------------------------------
__global__ __launch_bounds__(256) void gat_attn(
    const int* __restrict__ adj, const __hip_bfloat16* __restrict__ ht,
    const float* __restrict__ e1, const float* __restrict__ e2,
    float* __restrict__ accs, float* __restrict__ lsums)
{
    __shared__ __hip_bfloat16 hs[2][64 * HTS];   // 2 x 33792 B
    __shared__ unsigned msk32[64 * 33];          // 8448 B  [row][step(+pad)]
    __shared__ float e2s[JW];                    // 4096 B

    const int t     = threadIdx.x;
    const int lane  = t & 63;
    const int wv    = t >> 6;
    const int n16   = lane & 15;
    const int quad  = lane >> 4;
    const int split = blockIdx.x & (JSPLIT - 1);
    const int i0b   = (blockIdx.x >> 3) * 64;
    const int i0    = i0b + wv * 16;
    const int j0    = split * JW;
    const int rowl  = wv * 16 + n16;             // block-local row
    const int row   = i0 + n16;                  // global row

    // ---- adj slice -> LDS dword mask: msk32[r*33 + st], bit q*8+jj = edge ----
    {
        const int stt = t & 31;                  // step 0..31
        const int rr  = t >> 5;                  // 0..7
        #pragma unroll
        for (int rep = 0; rep < 8; ++rep) {
            const int r = rep * 8 + rr;
            const int* ap = adj + (size_t)(i0b + r) * NN + j0 + stt * 32;
            unsigned w = 0;
            #pragma unroll
            for (int k = 0; k < 8; ++k) {
                int4 v = *(const int4*)(ap + k * 4);
                unsigned nib =  (unsigned)(v.x > 0)
                             | ((unsigned)(v.y > 0) << 1)
                             | ((unsigned)(v.z > 0) << 2)
                             | ((unsigned)(v.w > 0) << 3);
                w |= nib << (k * 4);
            }
            msk32[r * 33 + stt] = w;
        }
    }
    // ---- e2 slice ----
    *(float4*)&e2s[t * 4] = *(const float4*)&e2[j0 + t * 4];
    // ---- ht sub-tile 0 -> hs[0] ----
    #pragma unroll
    for (int c = 0; c < 8; ++c) {
        int g = t + c * 256, f = g >> 5, jl = (g & 31) * 8;
        *(bf16x8*)&hs[0][f * HTS + jl] = *(const bf16x8*)&ht[(size_t)f * NN + j0 + jl];
    }
    __syncthreads();

    const float e1L = e1[row];
    float ms = e1L + MSHIFT * LOG2E;
    const float miL = ms > 0.f ? ms : GAT_ALPHA * ms;
    const float c0  = e1L - miL;                 // t0 = e2 + c0
    const float c1  = GAT_ALPHA * e1L - miL;     // t1 = fma(alpha, e2, c1)

    const float* ep0 = e2s + quad * 8;

    f32x4 dacc0 = {0.f,0.f,0.f,0.f}, dacc1 = {0.f,0.f,0.f,0.f};
    f32x4 dacc2 = {0.f,0.f,0.f,0.f}, dacc3 = {0.f,0.f,0.f,0.f};
    f32x4 dl    = {0.f,0.f,0.f,0.f};

    const i32x4 ones_i = {0x3F803F80, 0x3F803F80, 0x3F803F80, 0x3F803F80};
    const bf16x8 ones  = __builtin_bit_cast(bf16x8, ones_i);

    for (int sub = 0; sub < NSUB; ++sub) {
        const int buf = sub & 1;

        // issue next sub-tile's ht loads (in flight across the compute phase)
        bf16x8 hreg[8];
        if (sub + 1 < NSUB) {
            #pragma unroll
            for (int c = 0; c < 8; ++c) {
                int g = t + c * 256, f = g >> 5, jl = (g & 31) * 8;
                hreg[c] = *(const bf16x8*)&ht[(size_t)f * NN + j0 + (sub + 1) * SUBJ + jl];
            }
        }

        #pragma unroll
        for (int k = 0; k < SUBK; ++k) {
            const int stg = sub * SUBK + k;
            unsigned mw = msk32[rowl * 33 + stg];
            unsigned mc = mw >> (quad * 8);
            f32x4 e0 = *(const f32x4*)(ep0 + stg * 32);
            f32x4 ev = *(const f32x4*)(ep0 + stg * 32 + 4);
            const __hip_bfloat16* hb = &hs[buf][n16 * HTS + k * 32 + quad * 8];
            bf16x8 b0 = *(const bf16x8*)(hb);
            bf16x8 b1 = *(const bf16x8*)(hb + 16 * HTS);
            bf16x8 b2 = *(const bf16x8*)(hb + 32 * HTS);
            bf16x8 b3 = *(const bf16x8*)(hb + 48 * HTS);

#define PJ(eval, bit)                                                          \
            ( ((mc >> (bit)) & 1u)                                             \
                ? EXP2F(fmaxf(c0 + (eval), __builtin_fmaf(GAT_ALPHA, (eval), c1))) \
                : 0.f )
            float p0 = PJ(e0.x, 0);
            float p1 = PJ(e0.y, 1);
            float p2 = PJ(e0.z, 2);
            float p3 = PJ(e0.w, 3);
            float p4 = PJ(ev.x, 4);
            float p5 = PJ(ev.y, 5);
            float p6 = PJ(ev.z, 6);
            float p7 = PJ(ev.w, 7);
#undef PJ
            i32x4 iv;
            iv.x = (int)pack_bf16_rne(p1, p0);
            iv.y = (int)pack_bf16_rne(p3, p2);
            iv.z = (int)pack_bf16_rne(p5, p4);
            iv.w = (int)pack_bf16_rne(p7, p6);
            bf16x8 af = __builtin_bit_cast(bf16x8, iv);

            dacc0 = __builtin_amdgcn_mfma_f32_16x16x32_bf16(af, b0, dacc0, 0, 0, 0);
            dacc1 = __builtin_amdgcn_mfma_f32_16x16x32_bf16(af, b1, dacc1, 0, 0, 0);
            dacc2 = __builtin_amdgcn_mfma_f32_16x16x32_bf16(af, b2, dacc2, 0, 0, 0);
            dacc3 = __builtin_amdgcn_mfma_f32_16x16x32_bf16(af, b3, dacc3, 0, 0, 0);
            dl    = __builtin_amdgcn_mfma_f32_16x16x32_bf16(af, ones, dl, 0, 0, 0);
        }

        // commit prefetched ht to the other buffer; barrier flips ownership
        if (sub + 1 < NSUB) {
            #pragma unroll
            for (int c = 0; c < 8; ++c) {
                int g = t + c * 256, f = g >> 5, jl = (g & 31) * 8;
                *(bf16x8*)&hs[buf ^ 1][f * HTS + jl] = hreg[c];
            }
        }
        __syncthreads();
    }

    // dl D-tile: every column holds the row-sum; lanes n16==0 cover all 16 rows
    if (n16 == 0) {
        lsums[(size_t)split * NN + i0 + quad * 4 + 0] = dl.x;
        lsums[(size_t)split * NN + i0 + quad * 4 + 1] = dl.y;
        lsums[(size_t)split * NN + i0 + quad * 4 + 2] = dl.z;
        lsums[(size_t)split * NN + i0 + quad * 4 + 3] = dl.w;
    }

    // D layout: col = lane&15 (feature), row = quad*4 + reg (m89-verified)
    float* ab = accs + (size_t)split * NN * FF + (size_t)(i0 + quad * 4) * FF + n16;
#define STORE4(dv, ftofs)                                                      \
    ab[0 * FF + (ftofs)] = (dv).x;                                             \
    ab[1 * FF + (ftofs)] = (dv).y;                                             \
    ab[2 * FF + (ftofs)] = (dv).z;                                             \
    ab[3 * FF + (ftofs)] = (dv).w;
    STORE4(dacc0, 0)
    STORE4(dacc1, 16)
    STORE4(dacc2, 32)
    STORE4(dacc3, 48)
#undef STORE4
}

// ---------------------------------------------------------------------------
// Epilogue: out = elu( (sum_s accs[s]) / (sum_s lsums[s]) )
// ---------------------------------------------------------------------------
__global__ __launch_bounds__(256) void gat_epilogue(
    const float* __restrict__ accs, const float* __restrict__ lsums,
    float* __restrict__ out)
{
    const int idx = (blockIdx.x * 256 + threadIdx.x) * 4;  // 4 consecutive f, same row
    const int row = idx >> 6;

    float l = 0.f;
    #pragma unroll
    for (int s = 0; s < JSPLIT; ++s) l += lsums[(size_t)s * NN + row];

    f32x4 a = {0.f, 0.f, 0.f, 0.f};
    #pragma unroll
    for (int s = 0; s < JSPLIT; ++s) {
        f32x4 v = *(const f32x4*)(accs + (size_t)s * NN * FF + idx);
        a.x += v.x; a.y += v.y; a.z += v.z; a.w += v.w;
    }

    const float li = 1.f / l;
    f32x4 o;
    o.x = a.x * li; o.y = a.y * li; o.z = a.z * li; o.w = a.w * li;
    o.x = o.x > 0.f ? o.x : __expf(o.x) - 1.f;
    o.y = o.y > 0.f ? o.y : __expf(o.y) - 1.f;
    o.z = o.z > 0.f ? o.z : __expf(o.z) - 1.f;
    o.w = o.w > 0.f ? o.w : __expf(o.w) - 1.f;
    *(f32x4*)(out + idx) = o;
}

extern "C" void kernel_launch(void* const* d_in, const int* in_sizes, int n_in,
                              void* d_out, int out_size, void* d_ws, size_t ws_size,
                              hipStream_t stream) {
    const float* x   = (const float*)d_in[0];
    const int*   adj = (const int*)d_in[1];
    const float* W   = (const float*)d_in[2];
    const float* av  = (const float*)d_in[3];
    float* out = (float*)d_out;

    // ws: ht bf16[64*8192] (1MB) | e1 f32[8192] | e2 f32[8192]
    //     | accs f32[8][8192*64] (16MB) | lsums f32[8][8192] (256KB)
    char* wsb = (char*)d_ws;
    __hip_bfloat16* ht = (__hip_bfloat16*)wsb;
    float* e1    = (float*)(wsb + (1 << 20));
    float* e2    = e1 + NN;
    float* accs  = e2 + NN;
    float* lsums = accs + (size_t)JSPLIT * NN * FF;

    gat_linear<<<256, 256, 0, stream>>>(x, W, av, ht, e1, e2);
    gat_attn<<<(NN / 64) * JSPLIT, 256, 0, stream>>>(adj, ht, e1, e2, accs, lsums);
    gat_epilogue<<<NN * FF / 1024, 256, 0, stream>>>(accs, lsums, out);
}

// Round 12
// 403.779 us; speedup vs baseline: 1.0309x; 1.0309x over previous
//
#include <hip/hip_runtime.h>
#include <hip/hip_bf16.h>

#define NN 8192
#define KF 512
#define FF 64
#define GAT_ALPHA 0.2f
#define MSHIFT 20.0f          // safe upper bound on max_j e2[j] (pre-scale)
#define LOG2E 1.44269504f

#define JSPLIT 16             // grid = 128 row-groups x 16 = 2048 blocks
#define JW (NN / JSPLIT)      // 512 j per block
#define KSTEPS 16             // 16 k-steps of 32
#define PSTEP 8               // k-steps per ht phase (256 j)
#define HTS 264               // hs row stride (bf16): 132 dwords %32=4 -> 2-way (free)

#define EXP2F(x) __builtin_amdgcn_exp2f(x)

typedef __attribute__((ext_vector_type(8))) __bf16 bf16x8;
typedef __attribute__((ext_vector_type(4))) float f32x4;
typedef __attribute__((ext_vector_type(4))) int   i32x4;

// RNE fp32->bf16 pair pack, pure bit ops. Returns (bf16(hi)<<16)|bf16(lo).
__device__ __forceinline__ unsigned pack_bf16_rne(float hi, float lo) {
    unsigned uh = __float_as_uint(hi);
    unsigned ul = __float_as_uint(lo);
    uh = uh + 0x7FFFu + ((uh >> 16) & 1u);
    ul = ul + 0x7FFFu + ((ul >> 16) & 1u);
    return (uh & 0xFFFF0000u) | (ul >> 16);
}

// ---------------------------------------------------------------------------
// Kernel A: h = x@W (fp32), e1/e2 = (h@a1, h@a2) * log2(e),
//           ht = h^T bf16 [64][8192]. 256 blocks x 256 thr, 32 rows/block.
// ---------------------------------------------------------------------------
__global__ __launch_bounds__(256) void gat_linear(
    const float* __restrict__ x, const float* __restrict__ W,
    const float* __restrict__ av, __hip_bfloat16* __restrict__ ht,
    float* __restrict__ e1, float* __restrict__ e2)
{
    __shared__ float xs[32][33];
    __shared__ float Ws[32][64];
    __shared__ float ep[2][32][17];

    const int t  = threadIdx.x;
    const int fq = t & 15;
    const int rq = t >> 4;
    const int i0 = blockIdx.x * 32;

    const int kl = t & 31, r0 = t >> 5;
    const int fw = t & 63, kq = t >> 6;

    float acc[2][4] = {};

    for (int kt = 0; kt < KF; kt += 32) {
        #pragma unroll
        for (int m = 0; m < 4; ++m)
            xs[kl][r0 + 8 * m] = x[(size_t)(i0 + r0 + 8 * m) * KF + kt + kl];
        #pragma unroll
        for (int m = 0; m < 8; ++m)
            Ws[kq + 4 * m][fw] = W[(size_t)(kt + kq + 4 * m) * FF + fw];
        __syncthreads();
        #pragma unroll
        for (int kk = 0; kk < 32; ++kk) {
            float x0 = xs[kk][rq * 2];
            float x1 = xs[kk][rq * 2 + 1];
            f32x4 wv = *(const f32x4*)&Ws[kk][fq * 4];
            #pragma unroll
            for (int v = 0; v < 4; ++v) {
                acc[0][v] += x0 * wv[v];
                acc[1][v] += x1 * wv[v];
            }
        }
        __syncthreads();
    }

    #pragma unroll
    for (int v = 0; v < 4; ++v) {
        int f = fq * 4 + v;
        unsigned w = pack_bf16_rne(acc[1][v], acc[0][v]);
        *(unsigned*)&ht[(size_t)f * NN + i0 + rq * 2] = w;
    }

    f32x4 a1v = *(const f32x4*)&av[fq * 4];
    f32x4 a2v = *(const f32x4*)&av[64 + fq * 4];
    #pragma unroll
    for (int u = 0; u < 2; ++u) {
        float s1 = 0.f, s2 = 0.f;
        #pragma unroll
        for (int v = 0; v < 4; ++v) {
            s1 += acc[u][v] * a1v[v];
            s2 += acc[u][v] * a2v[v];
        }
        ep[0][rq * 2 + u][fq] = s1;
        ep[1][rq * 2 + u][fq] = s2;
    }
    __syncthreads();
    if (t < 32) {
        float s1 = 0.f, s2 = 0.f;
        #pragma unroll
        for (int q = 0; q < 16; ++q) { s1 += ep[0][t][q]; s2 += ep[1][t][q]; }
        e1[i0 + t] = s1 * LOG2E;
        e2[i0 + t] = s2 * LOG2E;
    }
}

// ---------------------------------------------------------------------------
// Kernel B: LDS-resident hot loop (R10 structure) with LDS cut to ~40 KB ->
// 4 blocks/CU (16 waves, 4/SIMD; R10 was 2 blocks/CU and latency-bound).
// Block = 64 rows x 512 j. Prologue: adj slice 128KB (coalesced, read once
// grid-wide) -> LDS dword mask msk32[row][step]; e2 2KB. ht staged in TWO
// sequential 256-j halves into a single 33.8KB buffer:
//   stage(ph) -> barrier -> 8 k-steps -> barrier -> stage(ph+1) ...
// Loop body: only ds_read + VALU + MFMA. 4 feature-MFMAs + 1 ones-MFMA (=l).
// ---------------------------------------------------------------------------
__global__ __launch_bounds__(256, 4) void gat_attn(
    const int* __restrict__ adj, const __hip_bfloat16* __restrict__ ht,
    const float* __restrict__ e1, const float* __restrict__ e2,
    float* __restrict__ accs, float* __restrict__ lsums)
{
    __shared__ __hip_bfloat16 hs[64 * HTS];      // 33792 B (one 256-j half)
    __shared__ unsigned msk32[64 * 17];          // 4352 B  [row][step(+pad)]
    __shared__ float e2s[JW];                    // 2048 B   -> total 40192 B

    const int t     = threadIdx.x;
    const int lane  = t & 63;
    const int wv    = t >> 6;
    const int n16   = lane & 15;
    const int quad  = lane >> 4;
    const int split = blockIdx.x & (JSPLIT - 1);
    const int i0b   = (blockIdx.x >> 4) * 64;
    const int i0    = i0b + wv * 16;
    const int j0    = split * JW;
    const int rowl  = wv * 16 + n16;             // block-local row
    const int row   = i0 + n16;                  // global row

    // ---- adj slice -> LDS dword mask: msk32[r*17 + st], bit q*8+jj = edge ----
    {
        const int stt = t & 15;                  // step 0..15
        const int rr  = t >> 4;                  // 0..15
        #pragma unroll
        for (int rep = 0; rep < 4; ++rep) {
            const int r = rep * 16 + rr;
            const int* ap = adj + (size_t)(i0b + r) * NN + j0 + stt * 32;
            unsigned w = 0;
            #pragma unroll
            for (int k = 0; k < 8; ++k) {
                int4 v = *(const int4*)(ap + k * 4);
                unsigned nib =  (unsigned)(v.x > 0)
                             | ((unsigned)(v.y > 0) << 1)
                             | ((unsigned)(v.z > 0) << 2)
                             | ((unsigned)(v.w > 0) << 3);
                w |= nib << (k * 4);
            }
            msk32[r * 17 + stt] = w;
        }
    }
    // ---- e2 slice ----
    if (t < JW / 4)
        *(float4*)&e2s[t * 4] = *(const float4*)&e2[j0 + t * 4];

    const float e1L = e1[row];
    float ms = e1L + MSHIFT * LOG2E;
    const float miL = ms > 0.f ? ms : GAT_ALPHA * ms;
    const float c0  = e1L - miL;                 // t0 = e2 + c0
    const float c1  = GAT_ALPHA * e1L - miL;     // t1 = fma(alpha, e2, c1)

    const float* ep0 = e2s + quad * 8;

    f32x4 dacc0 = {0.f,0.f,0.f,0.f}, dacc1 = {0.f,0.f,0.f,0.f};
    f32x4 dacc2 = {0.f,0.f,0.f,0.f}, dacc3 = {0.f,0.f,0.f,0.f};
    f32x4 dl    = {0.f,0.f,0.f,0.f};

    const i32x4 ones_i = {0x3F803F80, 0x3F803F80, 0x3F803F80, 0x3F803F80};
    const bf16x8 ones  = __builtin_bit_cast(bf16x8, ones_i);

    #pragma unroll
    for (int ph = 0; ph < 2; ++ph) {
        // ---- stage ht half: [64 features][256 j], coalesced bf16x8 ----
        #pragma unroll
        for (int c = 0; c < 8; ++c) {
            int g = t + c * 256, f = g >> 5, jl = (g & 31) * 8;
            *(bf16x8*)&hs[f * HTS + jl] =
                *(const bf16x8*)&ht[(size_t)f * NN + j0 + ph * 256 + jl];
        }
        __syncthreads();

        #pragma unroll
        for (int k = 0; k < PSTEP; ++k) {
            const int stg = ph * PSTEP + k;
            unsigned mw = msk32[rowl * 17 + stg];
            unsigned mc = mw >> (quad * 8);
            f32x4 e0 = *(const f32x4*)(ep0 + stg * 32);
            f32x4 ev = *(const f32x4*)(ep0 + stg * 32 + 4);
            const __hip_bfloat16* hb = &hs[n16 * HTS + k * 32 + quad * 8];
            bf16x8 b0 = *(const bf16x8*)(hb);
            bf16x8 b1 = *(const bf16x8*)(hb + 16 * HTS);
            bf16x8 b2 = *(const bf16x8*)(hb + 32 * HTS);
            bf16x8 b3 = *(const bf16x8*)(hb + 48 * HTS);

#define PJ(eval, bit)                                                          \
            ( ((mc >> (bit)) & 1u)                                             \
                ? EXP2F(fmaxf(c0 + (eval), __builtin_fmaf(GAT_ALPHA, (eval), c1))) \
                : 0.f )
            float p0 = PJ(e0.x, 0);
            float p1 = PJ(e0.y, 1);
            float p2 = PJ(e0.z, 2);
            float p3 = PJ(e0.w, 3);
            float p4 = PJ(ev.x, 4);
            float p5 = PJ(ev.y, 5);
            float p6 = PJ(ev.z, 6);
            float p7 = PJ(ev.w, 7);
#undef PJ
            i32x4 iv;
            iv.x = (int)pack_bf16_rne(p1, p0);
            iv.y = (int)pack_bf16_rne(p3, p2);
            iv.z = (int)pack_bf16_rne(p5, p4);
            iv.w = (int)pack_bf16_rne(p7, p6);
            bf16x8 af = __builtin_bit_cast(bf16x8, iv);

            dacc0 = __builtin_amdgcn_mfma_f32_16x16x32_bf16(af, b0, dacc0, 0, 0, 0);
            dacc1 = __builtin_amdgcn_mfma_f32_16x16x32_bf16(af, b1, dacc1, 0, 0, 0);
            dacc2 = __builtin_amdgcn_mfma_f32_16x16x32_bf16(af, b2, dacc2, 0, 0, 0);
            dacc3 = __builtin_amdgcn_mfma_f32_16x16x32_bf16(af, b3, dacc3, 0, 0, 0);
            dl    = __builtin_amdgcn_mfma_f32_16x16x32_bf16(af, ones, dl, 0, 0, 0);
        }
        if (ph == 0) __syncthreads();   // WAR: all waves done before restage
    }

    // dl D-tile: every column holds the row-sum; lanes n16==0 cover all 16 rows
    if (n16 == 0) {
        lsums[(size_t)split * NN + i0 + quad * 4 + 0] = dl.x;
        lsums[(size_t)split * NN + i0 + quad * 4 + 1] = dl.y;
        lsums[(size_t)split * NN + i0 + quad * 4 + 2] = dl.z;
        lsums[(size_t)split * NN + i0 + quad * 4 + 3] = dl.w;
    }

    // D layout: col = lane&15 (feature), row = quad*4 + reg (m89-verified)
    float* ab = accs + (size_t)split * NN * FF + (size_t)(i0 + quad * 4) * FF + n16;
#define STORE4(dv, ftofs)                                                      \
    ab[0 * FF + (ftofs)] = (dv).x;                                             \
    ab[1 * FF + (ftofs)] = (dv).y;                                             \
    ab[2 * FF + (ftofs)] = (dv).z;                                             \
    ab[3 * FF + (ftofs)] = (dv).w;
    STORE4(dacc0, 0)
    STORE4(dacc1, 16)
    STORE4(dacc2, 32)
    STORE4(dacc3, 48)
#undef STORE4
}

// ---------------------------------------------------------------------------
// Epilogue: out = elu( (sum_s accs[s]) / (sum_s lsums[s]) )
// ---------------------------------------------------------------------------
__global__ __launch_bounds__(256) void gat_epilogue(
    const float* __restrict__ accs, const float* __restrict__ lsums,
    float* __restrict__ out)
{
    const int idx = (blockIdx.x * 256 + threadIdx.x) * 4;  // 4 consecutive f, same row
    const int row = idx >> 6;

    float l = 0.f;
    #pragma unroll
    for (int s = 0; s < JSPLIT; ++s) l += lsums[(size_t)s * NN + row];

    f32x4 a = {0.f, 0.f, 0.f, 0.f};
    #pragma unroll
    for (int s = 0; s < JSPLIT; ++s) {
        f32x4 v = *(const f32x4*)(accs + (size_t)s * NN * FF + idx);
        a.x += v.x; a.y += v.y; a.z += v.z; a.w += v.w;
    }

    const float li = 1.f / l;
    f32x4 o;
    o.x = a.x * li; o.y = a.y * li; o.z = a.z * li; o.w = a.w * li;
    o.x = o.x > 0.f ? o.x : __expf(o.x) - 1.f;
    o.y = o.y > 0.f ? o.y : __expf(o.y) - 1.f;
    o.z = o.z > 0.f ? o.z : __expf(o.z) - 1.f;
    o.w = o.w > 0.f ? o.w : __expf(o.w) - 1.f;
    *(f32x4*)(out + idx) = o;
}

extern "C" void kernel_launch(void* const* d_in, const int* in_sizes, int n_in,
                              void* d_out, int out_size, void* d_ws, size_t ws_size,
                              hipStream_t stream) {
    const float* x   = (const float*)d_in[0];
    const int*   adj = (const int*)d_in[1];
    const float* W   = (const float*)d_in[2];
    const float* av  = (const float*)d_in[3];
    float* out = (float*)d_out;

    // ws: ht bf16[64*8192] (1MB) | e1 f32[8192] | e2 f32[8192]
    //     | accs f32[16][8192*64] (32MB) | lsums f32[16][8192] (512KB)
    char* wsb = (char*)d_ws;
    __hip_bfloat16* ht = (__hip_bfloat16*)wsb;
    float* e1    = (float*)(wsb + (1 << 20));
    float* e2    = e1 + NN;
    float* accs  = e2 + NN;
    float* lsums = accs + (size_t)JSPLIT * NN * FF;

    gat_linear<<<256, 256, 0, stream>>>(x, W, av, ht, e1, e2);
    gat_attn<<<(NN / 64) * JSPLIT, 256, 0, stream>>>(adj, ht, e1, e2, accs, lsums);
    gat_epilogue<<<NN * FF / 1024, 256, 0, stream>>>(accs, lsums, out);
}